// Round 11
// baseline (855.401 us; speedup 1.0000x reference)
//
#include <hip/hip_runtime.h>
#include <hip/hip_bf16.h>
#include <cstdint>

typedef __bf16 bf16x8 __attribute__((ext_vector_type(8)));
typedef float  f32x4  __attribute__((ext_vector_type(4)));

// ---------------- workspace layout (bytes) ----------------
constexpr size_t WTP_OFF  = 0;         // [24][256][192] bf16 prolog W^T
constexpr size_t WTHH_OFF = 2359296;   // [24][192][64]  bf16 W_hh^T per node
constexpr size_t WTFC_OFF = 2949120;   // [24][64][64]   bf16 W_fc^T per node
constexpr size_t GN_OFF   = 3145728;   // [4][24][24] f32 row-L1-normalized
constexpr size_t BGI_OFF  = 3154944;   // [24][192] f32 folded gi bias
constexpr size_t BHN2_OFF = 3173376;   // [64 j][24 n] f32 b_hh n-slice, n-contig
constexpr size_t BFC2_OFF = 3179520;   // [64 o][24 n] f32 b_fc, n-contig
constexpr size_t TWS_OFF  = 3185664;   // [2048][24][256] bf16 prolog GEMM result
constexpr size_t GIWS_OFF = 28351488;  // [2048][192][24] bf16 gi (n innermost)
constexpr size_t H0WS_OFF = 47225856;  // [2048][24][64] bf16 h0
constexpr size_t WS_NEED  = 53517312;

// t_l (R2-verified): [512 c][8 octet][8 mm] ushort, 64 KB; octets 0-3 used, q=3 zero-pad.
#define BLK(c,q) ((((q) ^ ((c)&3)) | ((((c)>>2)&1)<<2)))
// h_l (ushort index): [n][b][i], b in [0,8), i XOR-swizzled by b and n (R2-verified)
#define HL(n,b,i) ((((n)*8+(b))<<6) + ((i) ^ (((b)&7)<<3) ^ ((((n)>>2)&3)<<4)))

__device__ __forceinline__ float bf2f(ushort u){
  union { uint32_t i; float f; } v; v.i = ((uint32_t)u) << 16; return v.f;
}
__device__ __forceinline__ ushort f2bf(float f){
  union { float f; uint32_t i; } v; v.f = f;
  return (ushort)((v.i + 0x7fffu + ((v.i >> 16) & 1u)) >> 16);
}
__device__ __forceinline__ f32x4 mfma16(bf16x8 a, bf16x8 b, f32x4 c){
  return __builtin_amdgcn_mfma_f32_16x16x32_bf16(a, b, c, 0, 0, 0);
}
__device__ __forceinline__ float sigmoidf_(float x){
  float e = __expf(-x); return __builtin_amdgcn_rcpf(1.f + e);
}
__device__ __forceinline__ float tanhf_(float x){
  float e = __expf(-2.f*fabsf(x));
  float r = (1.f - e)*__builtin_amdgcn_rcpf(1.f + e);
  return copysignf(r, x);
}

// ---------------- G row-normalize ----------------
__global__ void k_gnorm(const float* g0, const float* g1, const float* g2, const float* g3, float* gn){
  int t = threadIdx.x;
  if (t >= 96) return;
  int mat = t / 24, row = t % 24;
  const float* G = (mat==0)? g0 : (mat==1)? g1 : (mat==2)? g2 : g3;
  float s = 0.f;
  for (int m=0;m<24;m++) s += fabsf(G[row*24+m]);
  float inv = 1.f/s;
  for (int m=0;m<24;m++) gn[mat*576 + row*24 + m] = G[row*24+m]*inv;
}

// ---------------- weight transpose/cast + bias prep ----------------
__global__ void k_prep(const float* Wih, const float* Winit, const float* Whh, const float* Wfc,
                       const float* bih, const float* bhh, const float* bfc,
                       ushort* wtp, ushort* wthh, ushort* wtfc, float* bgi,
                       float* bhn2, float* bfc2){
  int stride = gridDim.x*blockDim.x;
  int t0 = blockIdx.x*blockDim.x + threadIdx.x;
  for (int f = t0; f < 884736; f += stride){
    int m = f/36864, rr = f - m*36864, o = rr/192, i = rr - o*192;
    wtp[((size_t)m*256 + o)*192 + i] = f2bf(Wih[(size_t)m*36864 + i*192 + o]);
  }
  for (int f = t0; f < 294912; f += stride){
    int m = f/12288, rr = f - m*12288, o = rr/192, i = rr - o*192;
    wtp[((size_t)m*256 + 192 + o)*192 + i] = f2bf(Winit[(size_t)m*12288 + i*64 + o]);
  }
  for (int f = t0; f < 294912; f += stride){
    int m = f/12288, rr = f - m*12288, o = rr/64, i = rr - o*64;
    wthh[((size_t)m*192 + o)*64 + i] = f2bf(Whh[(size_t)m*12288 + i*192 + o]);
  }
  for (int f = t0; f < 98304; f += stride){
    int m = f/4096, rr = f - m*4096, o = rr/64, i = rr - o*64;
    wtfc[((size_t)m*64 + o)*64 + i] = f2bf(Wfc[(size_t)m*4096 + i*64 + o]);
  }
  for (int f = t0; f < 4608; f += stride){
    int o = f % 192;
    bgi[f] = bih[f] + ((o<128) ? bhh[f] : 0.f);
  }
  for (int f = t0; f < 1536; f += stride){
    int o = f/24, n = f - o*24;
    bhn2[f] = bhh[n*192 + 128 + o];
    bfc2[f] = bfc[n*64 + o];
  }
}

// ---------------- prolog per-node GEMM: rec(64b x 192) @ W^T -> t_ws ----------------
__global__ __launch_bounds__(256) void k_p1(const float* x, const float* h, const ushort* wtp,
                                            ushort* t_ws, int tsel, int o_base, int ntt){
  __shared__ ushort A_lds[64*192];
  int tid = threadIdx.x, w = tid>>6, l = tid&63;
  int m = blockIdx.x, b0 = blockIdx.y*64;
  for (int f = tid; f < 64*192; f += 256){
    int b = f/192, i = f - b*192;
    float v = (i < 64) ? x[((size_t)(b0+b)*3 + tsel)*1536 + m*64 + i]
                       : h[((size_t)(b0+b)*24 + m)*128 + (i-64)];
    A_lds[b*192 + (i ^ ((b&7)<<3))] = f2bf(v);
  }
  __syncthreads();
  for (int mt=0; mt<4; mt++){
    for (int nt = w; nt < ntt; nt += 4){
      f32x4 acc = {0.f,0.f,0.f,0.f};
      int rowb = mt*16 + (l&15);
      int og = o_base + nt*16 + (l&15);
      #pragma unroll
      for (int kc=0;kc<6;kc++){
        int i0 = kc*32 + ((l>>4)<<3);
        bf16x8 av = __builtin_bit_cast(bf16x8, *(const uint4*)(A_lds + rowb*192 + (i0 ^ ((rowb&7)<<3))));
        bf16x8 bv = __builtin_bit_cast(bf16x8, *(const uint4*)(wtp + ((size_t)m*256 + og)*192 + i0));
        acc = mfma16(av, bv, acc);
      }
      #pragma unroll
      for (int r=0;r<4;r++){
        int bp = mt*16 + ((l>>4)<<2) + r;
        t_ws[((size_t)(b0+bp)*24 + m)*256 + og] = f2bf(acc[r]);
      }
    }
  }
}

// ---------------- prolog mix: gi = Gn_ih @ t + bias ; h0 = Gn_init @ t + b_init ----------------
__global__ __launch_bounds__(256) void k_p2(const ushort* t_ws, const float* gn, const float* bgi,
                                            const float* binit, ushort* gi_ws, ushort* h0_ws){
  __shared__ ushort t_l[24*256];
  int tid = threadIdx.x; size_t b = blockIdx.x;
  const uint4* src = (const uint4*)(t_ws + b*6144);
  uint4* dst = (uint4*)t_l;
  for (int f = tid; f < 768; f += 256) dst[f] = src[f];
  __syncthreads();
  int o = tid;
  float acc[24];
  if (o < 192){
    const float* gih = gn + 576;
    #pragma unroll
    for (int n=0;n<24;n++) acc[n] = bgi[n*192+o];
    for (int m=0;m<24;m++){
      float tv = bf2f(t_l[m*256+o]);
      #pragma unroll
      for (int n=0;n<24;n++) acc[n] = fmaf(gih[n*24+m], tv, acc[n]);
    }
    uint ov[12];
    #pragma unroll
    for (int q=0;q<12;q++) ov[q] = (uint)f2bf(acc[2*q]) | ((uint)f2bf(acc[2*q+1])<<16);
    uint4* gdst = (uint4*)(gi_ws + (b*192 + o)*24);
    gdst[0] = make_uint4(ov[0],ov[1],ov[2],ov[3]);
    gdst[1] = make_uint4(ov[4],ov[5],ov[6],ov[7]);
    gdst[2] = make_uint4(ov[8],ov[9],ov[10],ov[11]);
  } else {
    int o2 = o - 192;
    const float* gin = gn;
    #pragma unroll
    for (int n=0;n<24;n++) acc[n] = binit[n*64+o2];
    for (int m=0;m<24;m++){
      float tv = bf2f(t_l[m*256 + 192 + o2]);
      #pragma unroll
      for (int n=0;n<24;n++) acc[n] = fmaf(gin[n*24+m], tv, acc[n]);
    }
    #pragma unroll
    for (int n=0;n<24;n++) h0_ws[(b*24+n)*64 + o2] = f2bf(acc[n]);
  }
}

// ---------------- x_t passthrough (NT stores) ----------------
__global__ void k_copy(const f32x4* x, f32x4* out2){
  int i = blockIdx.x*blockDim.x + threadIdx.x;
  for (; i < 2048*384; i += gridDim.x*blockDim.x){
    int b = i/384; int r = i - b*384;
    f32x4 v = x[(size_t)b*1152 + 768 + r];
    __builtin_nontemporal_store(v, &out2[i]);
  }
}

// ---------------- main GRU loop: 256 blocks x 8-batch tile, 16 waves (4/SIMD) ----------------
// In-phase ILP batching: all weight loads of a phase issue before the MFMAs consume them.
__global__ __launch_bounds__(1024,4) void k_main(const ushort* giws, const ushort* h0ws,
    const ushort* wthh, const ushort* wtfc, const float* gn,
    const float* bhn2, const float* bfc2, float* out){
  __shared__ ushort h_l[12288];   // 24n x 8b x 64i, swizzled (24.6 KB)
  __shared__ ushort t_l[32768];   // 512c x 64 (64 KB), BLK octet layout
  __shared__ float bhn_l[1568];   // [o][n], zero-padded tail
  __shared__ float bfc_l[1568];
  const int tid = threadIdx.x, w = tid>>6, l = tid&63;
  const int lr = l&15, lq = l>>4;
  const int b0 = blockIdx.x*8;

  for (int f = tid; f < 1568; f += 1024){
    bhn_l[f] = (f < 1536) ? bhn2[f] : 0.f;
    bfc_l[f] = (f < 1536) ? bfc2[f] : 0.f;
  }
  // zero the q=3 pad octets once
  for (int f = tid; f < 4096; f += 1024){
    int c = f>>3, mm = f&7;
    t_l[(c<<6) + (BLK(c,3)<<3) + mm] = 0;
  }
  // stage h0 -> h_l (swizzled)
  for (int f = tid; f < 3072; f += 1024){
    int idx = f<<2; int b = idx/1536; int r2 = idx - b*1536; int n = r2>>6; int i = r2&63;
    ushort4 v = *(const ushort4*)(h0ws + (size_t)(b0+b)*1536 + r2);
    *(ushort4*)(h_l + HL(n,b,i)) = v;
  }
  // constant Gn A-fragments (rows n, k=m, zero-padded)
  bf16x8 gnhh[2], gnfc[2];
  #pragma unroll
  for (int nt2=0; nt2<2; nt2++){
    union { ushort s[8]; bf16x8 v; } uh, uf;
    int row = nt2*16 + lr;
    #pragma unroll
    for (int jj=0;jj<8;jj++){
      int m = lq*8 + jj;
      bool ok = (row<24) && (m<24);
      uh.s[jj] = ok ? f2bf(gn[2*576 + row*24 + m]) : (ushort)0;
      uf.s[jj] = ok ? f2bf(gn[3*576 + row*24 + m]) : (ushort)0;
    }
    gnhh[nt2] = uh.v; gnfc[nt2] = uf.v;
  }
  // per-task mix coordinates (4 mix tasks/wave) + step-invariant gi fragments in regs
  int cb[4], co[4], cn0[4];
  ushort4 gih0[4], gih1[4], gih2[4];
  #pragma unroll
  for (int k=0;k<4;k++){
    int tId = w + k*16, ct = tId>>1, nt2 = tId&1;
    int c = ct*16 + lr;
    cb[k] = c>>6; co[k] = c&63; cn0[k] = nt2*16 + lq*4;
    size_t base = ((size_t)(b0+cb[k])*192 + co[k])*24 + cn0[k];
    gih0[k] = *(const ushort4*)(giws + base);            // r  (slice 0)
    gih1[k] = *(const ushort4*)(giws + base + 64*24);    // u  (slice 1)
    gih2[k] = *(const ushort4*)(giws + base + 128*24);   // n  (slice 2)
  }
  __syncthreads();

  float g1[4][4];   // r-gate, then nn
  for (int step=0; step<16; step++){
    // phases: p=0 -> r (W cols 0-63), p=1 -> n (cols 128-191), p=2 -> u (cols 64-127)
    #pragma unroll 1
    for (int p=0; p<3; p++){
      const int gs = (p==0) ? 0 : (p==1) ? 2 : 1;
      __syncthreads();
      // ---- batch-issue ALL weight loads for this phase (ILP), then consume
      uint4 wv0[6], wv1[6];
      #pragma unroll
      for (int k=0;k<6;k++){
        int tId = w + k*16, m = tId>>2, nt = tId&3;
        int o_loc = nt*16 + lr;
        const ushort* wb = wthh + (((size_t)m*192 + gs*64 + o_loc)<<6);
        wv0[k] = *(const uint4*)(wb + lq*8);
        wv1[k] = *(const uint4*)(wb + 32 + lq*8);
      }
      #pragma unroll
      for (int k=0;k<6;k++){
        int tId = w + k*16, m = tId>>2, nt = tId&3;
        int o_loc = nt*16 + lr;
        bf16x8 av0 = __builtin_bit_cast(bf16x8, *(const uint4*)(h_l + HL(m, lr&7, lq*8)));
        f32x4 acc = mfma16(av0, __builtin_bit_cast(bf16x8, wv0[k]), (f32x4){0.f,0.f,0.f,0.f});
        bf16x8 av1 = __builtin_bit_cast(bf16x8, *(const uint4*)(h_l + HL(m, lr&7, 32 + lq*8)));
        acc = mfma16(av1, __builtin_bit_cast(bf16x8, wv1[k]), acc);
        if (l < 32){
          #pragma unroll
          for (int r=0;r<4;r++){
            int bp = lq*4 + r, c = (bp<<6) + o_loc;
            t_l[(c<<6) + (BLK(c, m>>3)<<3) + (m&7)] = f2bf(acc[r]);
          }
        }
      }
      __syncthreads();
      // node mix (4 tasks/wave) + gate math
      #pragma unroll
      for (int k=0;k<4;k++){
        int tId = w + k*16, nt2 = tId&1;
        int c = (tId>>1)*16 + lr;
        f32x4 cin;
        if (p==1){
          cin = *(const f32x4*)(bhn_l + co[k]*24 + cn0[k]);
        } else {
          ushort4 gp = (p==0) ? gih0[k] : gih1[k];
          cin[0]=bf2f(gp.x); cin[1]=bf2f(gp.y); cin[2]=bf2f(gp.z); cin[3]=bf2f(gp.w);
        }
        bf16x8 bv = __builtin_bit_cast(bf16x8, *(const uint4*)(t_l + (c<<6) + (BLK(c,lq)<<3)));
        f32x4 fa = mfma16(gnhh[nt2], bv, cin);
        if (p==0){
          #pragma unroll
          for (int r=0;r<4;r++) g1[k][r] = sigmoidf_(fa[r]);
        } else if (p==1){
          ushort4 gp = gih2[k];
          float gin[4] = { bf2f(gp.x), bf2f(gp.y), bf2f(gp.z), bf2f(gp.w) };
          #pragma unroll
          for (int r=0;r<4;r++) g1[k][r] = tanhf_(gin[r] + g1[k][r]*fa[r]);
        } else {
          #pragma unroll
          for (int r=0;r<4;r++){
            int n = cn0[k] + r;
            if (n < 24){
              float ug = sigmoidf_(fa[r]);
              float hp = bf2f(h_l[HL(n, cb[k], co[k])]);
              float hv = (1.f-ug)*g1[k][r] + ug*hp;
              h_l[HL(n, cb[k], co[k])] = f2bf(hv);
            }
          }
        }
      }
    }
    __syncthreads();
    // fc t2-GEMM (6 tasks/wave): batch-issue weight loads, then consume
    {
      uint4 wv0[6], wv1[6];
      #pragma unroll
      for (int k=0;k<6;k++){
        int tId = w + k*16, m = tId>>2, nt = tId&3;
        int o_loc = nt*16 + lr;
        const ushort* wb = wtfc + ((((size_t)m<<6) + o_loc)<<6);
        wv0[k] = *(const uint4*)(wb + lq*8);
        wv1[k] = *(const uint4*)(wb + 32 + lq*8);
      }
      #pragma unroll
      for (int k=0;k<6;k++){
        int tId = w + k*16, m = tId>>2, nt = tId&3;
        int o_loc = nt*16 + lr;
        bf16x8 av0 = __builtin_bit_cast(bf16x8, *(const uint4*)(h_l + HL(m, lr&7, lq*8)));
        f32x4 acc = mfma16(av0, __builtin_bit_cast(bf16x8, wv0[k]), (f32x4){0.f,0.f,0.f,0.f});
        bf16x8 av1 = __builtin_bit_cast(bf16x8, *(const uint4*)(h_l + HL(m, lr&7, 32 + lq*8)));
        acc = mfma16(av1, __builtin_bit_cast(bf16x8, wv1[k]), acc);
        if (l < 32){
          #pragma unroll
          for (int r=0;r<4;r++){
            int bp = lq*4 + r, c = (bp<<6) + o_loc;
            t_l[(c<<6) + (BLK(c, m>>3)<<3) + (m&7)] = f2bf(acc[r]);
          }
        }
      }
    }
    __syncthreads();
    // fc mix + tanh + NT store (4 tasks/wave)
    #pragma unroll
    for (int k=0;k<4;k++){
      int tId = w + k*16, nt2 = tId&1;
      int c = (tId>>1)*16 + lr;
      f32x4 cin = *(const f32x4*)(bfc_l + co[k]*24 + cn0[k]);
      bf16x8 bv = __builtin_bit_cast(bf16x8, *(const uint4*)(t_l + (c<<6) + (BLK(c,lq)<<3)));
      f32x4 fa = mfma16(gnfc[nt2], bv, cin);
      #pragma unroll
      for (int r=0;r<4;r++){
        int n = cn0[k] + r;
        if (n < 24){
          float y = tanhf_(fa[r]);
          __builtin_nontemporal_store(y,
            &out[((size_t)(b0+cb[k])*16 + step)*1536 + (n<<6) + co[k]]);
        }
      }
    }
  }
}

extern "C" void kernel_launch(void* const* d_in, const int* in_sizes, int n_in,
                              void* d_out, int out_size, void* d_ws, size_t ws_size,
                              hipStream_t stream){
  if (ws_size < WS_NEED) return;
  const float* x     = (const float*)d_in[0];
  const float* h     = (const float*)d_in[1];
  const float* Winit = (const float*)d_in[4];
  const float* binit = (const float*)d_in[5];
  const float* Ginit = (const float*)d_in[6];
  const float* Wih   = (const float*)d_in[7];
  const float* bih   = (const float*)d_in[8];
  const float* Gih   = (const float*)d_in[9];
  const float* Whh   = (const float*)d_in[10];
  const float* bhh   = (const float*)d_in[11];
  const float* Ghh   = (const float*)d_in[12];
  const float* Wfc   = (const float*)d_in[13];
  const float* bfc   = (const float*)d_in[14];
  const float* Gfc   = (const float*)d_in[15];
  char* ws = (char*)d_ws;
  ushort* wtp  = (ushort*)(ws + WTP_OFF);
  ushort* wthh = (ushort*)(ws + WTHH_OFF);
  ushort* wtfc = (ushort*)(ws + WTFC_OFF);
  float*  gn   = (float*)(ws + GN_OFF);
  float*  bgi  = (float*)(ws + BGI_OFF);
  float*  bhn2 = (float*)(ws + BHN2_OFF);
  float*  bfc2 = (float*)(ws + BFC2_OFF);
  ushort* tws  = (ushort*)(ws + TWS_OFF);
  ushort* giws = (ushort*)(ws + GIWS_OFF);
  ushort* h0ws = (ushort*)(ws + H0WS_OFF);
  float* out  = (float*)d_out;
  float* out2 = out + (size_t)2048*16*1536;

  k_gnorm<<<1, 128, 0, stream>>>(Ginit, Gih, Ghh, Gfc, gn);
  k_prep<<<512, 256, 0, stream>>>(Wih, Winit, Whh, Wfc, bih, bhh, bfc, wtp, wthh, wtfc, bgi, bhn2, bfc2);
  k_p1<<<dim3(24,32), 256, 0, stream>>>(x, h, wtp, tws, 2, 0, 12);
  k_p1<<<dim3(24,32), 256, 0, stream>>>(x, h, wtp, tws, 1, 192, 4);
  k_p2<<<2048, 256, 0, stream>>>(tws, gn, bgi, binit, giws, h0ws);
  k_copy<<<2048, 256, 0, stream>>>((const f32x4*)x, (f32x4*)out2);
  k_main<<<256, 1024, 0, stream>>>(giws, h0ws, wthh, wtfc, gn, bhn2, bfc2, out);
}

// Round 12
// 773.047 us; speedup vs baseline: 1.1065x; 1.1065x over previous
//
#include <hip/hip_runtime.h>
#include <hip/hip_bf16.h>
#include <cstdint>

typedef __bf16 bf16x8 __attribute__((ext_vector_type(8)));
typedef float  f32x4  __attribute__((ext_vector_type(4)));

// ---------------- workspace layout (bytes) ----------------
constexpr size_t WTP_OFF  = 0;         // [24][256][192] bf16 prolog W^T
constexpr size_t WTHH_OFF = 2359296;   // [24][192][64]  bf16 W_hh^T per node
constexpr size_t WTFC_OFF = 2949120;   // [24][64][64]   bf16 W_fc^T per node
constexpr size_t GN_OFF   = 3145728;   // [4][24][24] f32 row-L1-normalized
constexpr size_t BGI_OFF  = 3154944;   // [24][192] f32 folded gi bias
constexpr size_t BHN2_OFF = 3173376;   // [64 j][24 n] f32 b_hh n-slice, n-contig
constexpr size_t BFC2_OFF = 3179520;   // [64 o][24 n] f32 b_fc, n-contig
constexpr size_t TWS_OFF  = 3185664;   // [2048][24][256] bf16 prolog GEMM result
constexpr size_t GIWS_OFF = 28351488;  // [2048][192][24] bf16 gi (n innermost)
constexpr size_t H0WS_OFF = 47225856;  // [2048][24][64] bf16 h0
constexpr size_t WS_NEED  = 53517312;

// t_l: [2048 c][4 octet][8 mm] ushort (128 KB); c = b*256 + o (o<192: hh, o>=192: fc)
// 2-bit octet swizzle; (c>>8)&3 = batch b low bits, (c>>10)&3 = b high bit -> banks see b.
#define TOCT(c,q) ((((q) ^ ((c)&3) ^ (((c)>>2)&3) ^ (((c)>>8)&3) ^ (((c)>>10)&3)) & 3))
#define TIDX(c,q,mm) (((c)<<5) + (TOCT(c,q)<<3) + (mm))
// h_l (ushort index): [n][b][i], b in [0,8), i XOR-swizzled by b and n (R2-verified)
#define HL(n,b,i) ((((n)*8+(b))<<6) + ((i) ^ (((b)&7)<<3) ^ ((((n)>>2)&3)<<4)))

__device__ __forceinline__ float bf2f(ushort u){
  union { uint32_t i; float f; } v; v.i = ((uint32_t)u) << 16; return v.f;
}
__device__ __forceinline__ ushort f2bf(float f){
  union { float f; uint32_t i; } v; v.f = f;
  return (ushort)((v.i + 0x7fffu + ((v.i >> 16) & 1u)) >> 16);
}
__device__ __forceinline__ f32x4 mfma16(bf16x8 a, bf16x8 b, f32x4 c){
  return __builtin_amdgcn_mfma_f32_16x16x32_bf16(a, b, c, 0, 0, 0);
}
__device__ __forceinline__ float sigmoidf_(float x){
  float e = __expf(-x); return __builtin_amdgcn_rcpf(1.f + e);
}
__device__ __forceinline__ float tanhf_(float x){
  float e = __expf(-2.f*fabsf(x));
  float r = (1.f - e)*__builtin_amdgcn_rcpf(1.f + e);
  return copysignf(r, x);
}

// ---------------- G row-normalize ----------------
__global__ void k_gnorm(const float* g0, const float* g1, const float* g2, const float* g3, float* gn){
  int t = threadIdx.x;
  if (t >= 96) return;
  int mat = t / 24, row = t % 24;
  const float* G = (mat==0)? g0 : (mat==1)? g1 : (mat==2)? g2 : g3;
  float s = 0.f;
  for (int m=0;m<24;m++) s += fabsf(G[row*24+m]);
  float inv = 1.f/s;
  for (int m=0;m<24;m++) gn[mat*576 + row*24 + m] = G[row*24+m]*inv;
}

// ---------------- weight transpose/cast + bias prep ----------------
__global__ void k_prep(const float* Wih, const float* Winit, const float* Whh, const float* Wfc,
                       const float* bih, const float* bhh, const float* bfc,
                       ushort* wtp, ushort* wthh, ushort* wtfc, float* bgi,
                       float* bhn2, float* bfc2){
  int stride = gridDim.x*blockDim.x;
  int t0 = blockIdx.x*blockDim.x + threadIdx.x;
  for (int f = t0; f < 884736; f += stride){
    int m = f/36864, rr = f - m*36864, o = rr/192, i = rr - o*192;
    wtp[((size_t)m*256 + o)*192 + i] = f2bf(Wih[(size_t)m*36864 + i*192 + o]);
  }
  for (int f = t0; f < 294912; f += stride){
    int m = f/12288, rr = f - m*12288, o = rr/192, i = rr - o*192;
    wtp[((size_t)m*256 + 192 + o)*192 + i] = f2bf(Winit[(size_t)m*12288 + i*64 + o]);
  }
  for (int f = t0; f < 294912; f += stride){
    int m = f/12288, rr = f - m*12288, o = rr/64, i = rr - o*64;
    wthh[((size_t)m*192 + o)*64 + i] = f2bf(Whh[(size_t)m*12288 + i*192 + o]);
  }
  for (int f = t0; f < 98304; f += stride){
    int m = f/4096, rr = f - m*4096, o = rr/64, i = rr - o*64;
    wtfc[((size_t)m*64 + o)*64 + i] = f2bf(Wfc[(size_t)m*4096 + i*64 + o]);
  }
  for (int f = t0; f < 4608; f += stride){
    int o = f % 192;
    bgi[f] = bih[f] + ((o<128) ? bhh[f] : 0.f);
  }
  for (int f = t0; f < 1536; f += stride){
    int o = f/24, n = f - o*24;
    bhn2[f] = bhh[n*192 + 128 + o];
    bfc2[f] = bfc[n*64 + o];
  }
}

// ---------------- prolog per-node GEMM: rec(64b x 192) @ W^T -> t_ws ----------------
__global__ __launch_bounds__(256) void k_p1(const float* x, const float* h, const ushort* wtp,
                                            ushort* t_ws, int tsel, int o_base, int ntt){
  __shared__ ushort A_lds[64*192];
  int tid = threadIdx.x, w = tid>>6, l = tid&63;
  int m = blockIdx.x, b0 = blockIdx.y*64;
  for (int f = tid; f < 64*192; f += 256){
    int b = f/192, i = f - b*192;
    float v = (i < 64) ? x[((size_t)(b0+b)*3 + tsel)*1536 + m*64 + i]
                       : h[((size_t)(b0+b)*24 + m)*128 + (i-64)];
    A_lds[b*192 + (i ^ ((b&7)<<3))] = f2bf(v);
  }
  __syncthreads();
  for (int mt=0; mt<4; mt++){
    for (int nt = w; nt < ntt; nt += 4){
      f32x4 acc = {0.f,0.f,0.f,0.f};
      int rowb = mt*16 + (l&15);
      int og = o_base + nt*16 + (l&15);
      #pragma unroll
      for (int kc=0;kc<6;kc++){
        int i0 = kc*32 + ((l>>4)<<3);
        bf16x8 av = __builtin_bit_cast(bf16x8, *(const uint4*)(A_lds + rowb*192 + (i0 ^ ((rowb&7)<<3))));
        bf16x8 bv = __builtin_bit_cast(bf16x8, *(const uint4*)(wtp + ((size_t)m*256 + og)*192 + i0));
        acc = mfma16(av, bv, acc);
      }
      #pragma unroll
      for (int r=0;r<4;r++){
        int bp = mt*16 + ((l>>4)<<2) + r;
        t_ws[((size_t)(b0+bp)*24 + m)*256 + og] = f2bf(acc[r]);
      }
    }
  }
}

// ---------------- prolog mix: gi = Gn_ih @ t + bias ; h0 = Gn_init @ t + b_init ----------------
__global__ __launch_bounds__(256) void k_p2(const ushort* t_ws, const float* gn, const float* bgi,
                                            const float* binit, ushort* gi_ws, ushort* h0_ws){
  __shared__ ushort t_l[24*256];
  int tid = threadIdx.x; size_t b = blockIdx.x;
  const uint4* src = (const uint4*)(t_ws + b*6144);
  uint4* dst = (uint4*)t_l;
  for (int f = tid; f < 768; f += 256) dst[f] = src[f];
  __syncthreads();
  int o = tid;
  float acc[24];
  if (o < 192){
    const float* gih = gn + 576;
    #pragma unroll
    for (int n=0;n<24;n++) acc[n] = bgi[n*192+o];
    for (int m=0;m<24;m++){
      float tv = bf2f(t_l[m*256+o]);
      #pragma unroll
      for (int n=0;n<24;n++) acc[n] = fmaf(gih[n*24+m], tv, acc[n]);
    }
    uint ov[12];
    #pragma unroll
    for (int q=0;q<12;q++) ov[q] = (uint)f2bf(acc[2*q]) | ((uint)f2bf(acc[2*q+1])<<16);
    uint4* gdst = (uint4*)(gi_ws + (b*192 + o)*24);
    gdst[0] = make_uint4(ov[0],ov[1],ov[2],ov[3]);
    gdst[1] = make_uint4(ov[4],ov[5],ov[6],ov[7]);
    gdst[2] = make_uint4(ov[8],ov[9],ov[10],ov[11]);
  } else {
    int o2 = o - 192;
    const float* gin = gn;
    #pragma unroll
    for (int n=0;n<24;n++) acc[n] = binit[n*64+o2];
    for (int m=0;m<24;m++){
      float tv = bf2f(t_l[m*256 + 192 + o2]);
      #pragma unroll
      for (int n=0;n<24;n++) acc[n] = fmaf(gin[n*24+m], tv, acc[n]);
    }
    #pragma unroll
    for (int n=0;n<24;n++) h0_ws[(b*24+n)*64 + o2] = f2bf(acc[n]);
  }
}

// ---------------- x_t passthrough (NT stores) ----------------
__global__ void k_copy(const f32x4* x, f32x4* out2){
  int i = blockIdx.x*blockDim.x + threadIdx.x;
  for (; i < 2048*384; i += gridDim.x*blockDim.x){
    int b = i/384; int r = i - b*384;
    f32x4 v = x[(size_t)b*1152 + 768 + r];
    __builtin_nontemporal_store(v, &out2[i]);
  }
}

// ---------------- main GRU loop: 256 blocks x 8-batch tile, 16 waves, 2 barriers/step ----------------
// Phase A: fc-GEMM(s-1) + hh-GEMM(s)   (both read h_l = h after step s-1)
// Phase B: fc-mix(s-1)+NT-store + hh-mix(s) (writes h_new into h_l)
__global__ __launch_bounds__(1024,1) void k_main(const ushort* giws, const ushort* h0ws,
    const ushort* wthh, const ushort* wtfc, const float* gn,
    const float* bhn2, const float* bfc2, float* out){
  __shared__ ushort h_l[12288];    // 24n x 8b x 64i, swizzled (24.6 KB)
  __shared__ ushort t_l[65536];    // 2048c x 64B, TOCT layout (128 KB)
  const int tid = threadIdx.x, w = tid>>6, l = tid&63;
  const int lr = l&15, lq = l>>4;
  const int b0 = blockIdx.x*8;

  // zero the q=3 pad octets once
  for (int f = tid; f < 16384; f += 1024){
    int c = f>>3, mm = f&7;
    t_l[TIDX(c,3,mm)] = 0;
  }
  // stage h0 -> h_l (swizzled)
  for (int f = tid; f < 3072; f += 1024){
    int idx = f<<2; int b = idx/1536; int r2 = idx - b*1536; int n = r2>>6; int i = r2&63;
    ushort4 v = *(const ushort4*)(h0ws + (size_t)(b0+b)*1536 + r2);
    *(ushort4*)(h_l + HL(n,b,i)) = v;
  }
  // constant Gn A-fragments (rows n, k=m, zero-padded)
  bf16x8 gnhh[2], gnfc[2];
  #pragma unroll
  for (int nt2=0; nt2<2; nt2++){
    union { ushort s[8]; bf16x8 v; } uh, uf;
    int row = nt2*16 + lr;
    #pragma unroll
    for (int jj=0;jj<8;jj++){
      int m = lq*8 + jj;
      bool ok = (row<24) && (m<24);
      uh.s[jj] = ok ? f2bf(gn[2*576 + row*24 + m]) : (ushort)0;
      uf.s[jj] = ok ? f2bf(gn[3*576 + row*24 + m]) : (ushort)0;
    }
    gnhh[nt2] = uh.v; gnfc[nt2] = uf.v;
  }
  // per-task mix coordinates (4 tasks/wave) + step-invariant gi fragments in regs
  int mb[4], mo[4], mn0[4];
  ushort4 gih0[4], gih1[4], gih2[4];
  #pragma unroll
  for (int k=0;k<4;k++){
    int t = w + k*16;
    int b = t>>3, ot = (t>>1)&3, nt2 = t&1;
    mb[k] = b; mo[k] = ot*16 + lr; mn0[k] = nt2*16 + lq*4;
    size_t base = ((size_t)(b0+b)*192 + mo[k])*24 + mn0[k];
    gih0[k] = *(const ushort4*)(giws + base);            // r  (slice 0)
    gih1[k] = *(const ushort4*)(giws + base + 64*24);    // u  (slice 1)
    gih2[k] = *(const ushort4*)(giws + base + 128*24);   // n  (slice 2)
  }
  __syncthreads();

  #pragma unroll 1
  for (int s=0; s<=16; s++){
    __syncthreads();
    // ======== Phase A: GEMMs (read h_l, write t_l) ========
    if (s > 0){
      // fc-GEMM(s-1): 6 tasks/wave -> t_l cols 192-255
      #pragma unroll
      for (int k=0;k<6;k++){
        int tId = w + k*16, m = tId>>2, nt = tId&3;
        int o = nt*16 + lr;
        const ushort* wb = wtfc + ((((size_t)m<<6) + o)<<6);
        bf16x8 av0 = __builtin_bit_cast(bf16x8, *(const uint4*)(h_l + HL(m, lr&7, lq*8)));
        f32x4 acc = mfma16(av0, __builtin_bit_cast(bf16x8, *(const uint4*)(wb + lq*8)), (f32x4){0.f,0.f,0.f,0.f});
        bf16x8 av1 = __builtin_bit_cast(bf16x8, *(const uint4*)(h_l + HL(m, lr&7, 32 + lq*8)));
        acc = mfma16(av1, __builtin_bit_cast(bf16x8, *(const uint4*)(wb + 32 + lq*8)), acc);
        if (l < 32){
          #pragma unroll
          for (int r=0;r<4;r++){
            int c = (lq*4 + r)*256 + 192 + o;
            t_l[TIDX(c, m>>3, m&7)] = f2bf(acc[r]);
          }
        }
      }
    }
    if (s < 16){
      // hh-GEMM(s): 18 tasks/wave over all 192 W_hh cols -> t_l cols 0-191
      #pragma unroll 6
      for (int k=0;k<18;k++){
        int tId = w + k*16;
        int m = tId/12, col = tId - m*12;
        int o = col*16 + lr;
        const ushort* wb = wthh + (((size_t)m*192 + o)<<6);
        bf16x8 av0 = __builtin_bit_cast(bf16x8, *(const uint4*)(h_l + HL(m, lr&7, lq*8)));
        f32x4 acc = mfma16(av0, __builtin_bit_cast(bf16x8, *(const uint4*)(wb + lq*8)), (f32x4){0.f,0.f,0.f,0.f});
        bf16x8 av1 = __builtin_bit_cast(bf16x8, *(const uint4*)(h_l + HL(m, lr&7, 32 + lq*8)));
        acc = mfma16(av1, __builtin_bit_cast(bf16x8, *(const uint4*)(wb + 32 + lq*8)), acc);
        if (l < 32){
          #pragma unroll
          for (int r=0;r<4;r++){
            int c = (lq*4 + r)*256 + o;
            t_l[TIDX(c, m>>3, m&7)] = f2bf(acc[r]);
          }
        }
      }
    }
    __syncthreads();
    // ======== Phase B: mixes ========
    if (s > 0){
      // fc-mix(s-1): tanh + NT store (issues stores early; drain overlaps hh-mix)
      #pragma unroll
      for (int k=0;k<4;k++){
        int b = mb[k], co = mo[k], n0 = mn0[k];
        int nt2 = (w + k*16)&1;
        int c = b*256 + 192 + co;
        f32x4 cin = *(const f32x4*)(bfc2 + co*24 + n0);
        bf16x8 bv = __builtin_bit_cast(bf16x8, *(const uint4*)(t_l + (c<<5) + (TOCT(c,lq)<<3)));
        f32x4 fa = mfma16(gnfc[nt2], bv, cin);
        #pragma unroll
        for (int r=0;r<4;r++){
          int n = n0 + r;
          if (n < 24){
            float y = tanhf_(fa[r]);
            __builtin_nontemporal_store(y,
              &out[((size_t)(b0+b)*16 + (s-1))*1536 + (n<<6) + co]);
          }
        }
      }
    }
    if (s < 16){
      // hh-mix(s): fused r/u/n mix + gate math + h_l update
      #pragma unroll
      for (int k=0;k<4;k++){
        int b = mb[k], co = mo[k], n0 = mn0[k];
        int nt2 = (w + k*16)&1;
        int cr = b*256 + co;
        bf16x8 bvr = __builtin_bit_cast(bf16x8, *(const uint4*)(t_l + (cr<<5) + (TOCT(cr,lq)<<3)));
        int cu = cr + 64;
        bf16x8 bvu = __builtin_bit_cast(bf16x8, *(const uint4*)(t_l + (cu<<5) + (TOCT(cu,lq)<<3)));
        int cn = cr + 128;
        bf16x8 bvn = __builtin_bit_cast(bf16x8, *(const uint4*)(t_l + (cn<<5) + (TOCT(cn,lq)<<3)));
        ushort4 gr = gih0[k], gu = gih1[k], gnn = gih2[k];
        f32x4 cin_r = { bf2f(gr.x), bf2f(gr.y), bf2f(gr.z), bf2f(gr.w) };
        f32x4 cin_u = { bf2f(gu.x), bf2f(gu.y), bf2f(gu.z), bf2f(gu.w) };
        f32x4 cin_n = *(const f32x4*)(bhn2 + co*24 + n0);
        f32x4 fr = mfma16(gnhh[nt2], bvr, cin_r);
        f32x4 fu = mfma16(gnhh[nt2], bvu, cin_u);
        f32x4 fn = mfma16(gnhh[nt2], bvn, cin_n);
        float gin[4] = { bf2f(gnn.x), bf2f(gnn.y), bf2f(gnn.z), bf2f(gnn.w) };
        #pragma unroll
        for (int r=0;r<4;r++){
          int n = n0 + r;
          if (n < 24){
            float rg = sigmoidf_(fr[r]);
            float ug = sigmoidf_(fu[r]);
            float nn = tanhf_(gin[r] + rg*fn[r]);
            float hp = bf2f(h_l[HL(n, b, co)]);
            float hv = (1.f-ug)*nn + ug*hp;
            h_l[HL(n, b, co)] = f2bf(hv);
          }
        }
      }
    }
  }
}

extern "C" void kernel_launch(void* const* d_in, const int* in_sizes, int n_in,
                              void* d_out, int out_size, void* d_ws, size_t ws_size,
                              hipStream_t stream){
  if (ws_size < WS_NEED) return;
  const float* x     = (const float*)d_in[0];
  const float* h     = (const float*)d_in[1];
  const float* Winit = (const float*)d_in[4];
  const float* binit = (const float*)d_in[5];
  const float* Ginit = (const float*)d_in[6];
  const float* Wih   = (const float*)d_in[7];
  const float* bih   = (const float*)d_in[8];
  const float* Gih   = (const float*)d_in[9];
  const float* Whh   = (const float*)d_in[10];
  const float* bhh   = (const float*)d_in[11];
  const float* Ghh   = (const float*)d_in[12];
  const float* Wfc   = (const float*)d_in[13];
  const float* bfc   = (const float*)d_in[14];
  const float* Gfc   = (const float*)d_in[15];
  char* ws = (char*)d_ws;
  ushort* wtp  = (ushort*)(ws + WTP_OFF);
  ushort* wthh = (ushort*)(ws + WTHH_OFF);
  ushort* wtfc = (ushort*)(ws + WTFC_OFF);
  float*  gn   = (float*)(ws + GN_OFF);
  float*  bgi  = (float*)(ws + BGI_OFF);
  float*  bhn2 = (float*)(ws + BHN2_OFF);
  float*  bfc2 = (float*)(ws + BFC2_OFF);
  ushort* tws  = (ushort*)(ws + TWS_OFF);
  ushort* giws = (ushort*)(ws + GIWS_OFF);
  ushort* h0ws = (ushort*)(ws + H0WS_OFF);
  float* out  = (float*)d_out;
  float* out2 = out + (size_t)2048*16*1536;

  k_gnorm<<<1, 128, 0, stream>>>(Ginit, Gih, Ghh, Gfc, gn);
  k_prep<<<512, 256, 0, stream>>>(Wih, Winit, Whh, Wfc, bih, bhh, bfc, wtp, wthh, wtfc, bgi, bhn2, bfc2);
  k_p1<<<dim3(24,32), 256, 0, stream>>>(x, h, wtp, tws, 2, 0, 12);
  k_p1<<<dim3(24,32), 256, 0, stream>>>(x, h, wtp, tws, 1, 192, 4);
  k_p2<<<2048, 256, 0, stream>>>(tws, gn, bgi, binit, giws, h0ws);
  k_copy<<<2048, 256, 0, stream>>>((const f32x4*)x, (f32x4*)out2);
  k_main<<<256, 1024, 0, stream>>>(giws, h0ws, wthh, wtfc, gn, bhn2, bfc2, out);
}

// Round 13
// 586.365 us; speedup vs baseline: 1.4588x; 1.3184x over previous
//
#include <hip/hip_runtime.h>
#include <hip/hip_bf16.h>
#include <cstdint>

typedef __bf16 bf16x8 __attribute__((ext_vector_type(8)));
typedef float  f32x4  __attribute__((ext_vector_type(4)));

// ---------------- workspace layout (bytes) ----------------
constexpr size_t WTP_OFF  = 0;         // [24][256][192] bf16 prolog W^T
constexpr size_t WTHH_OFF = 2359296;   // [24][192][64]  bf16 W_hh^T per node
constexpr size_t WTFC_OFF = 2949120;   // [24][64][64]   bf16 W_fc^T per node
constexpr size_t GN_OFF   = 3145728;   // [4][24][24] f32 row-L1-normalized
constexpr size_t BGI_OFF  = 3154944;   // [24][192] f32 folded gi bias
constexpr size_t BHN2_OFF = 3173376;   // [64 j][24 n] f32 b_hh n-slice, n-contig
constexpr size_t BFC2_OFF = 3179520;   // [64 o][24 n] f32 b_fc, n-contig
constexpr size_t TWS_OFF  = 3185664;   // [2048][24][256] bf16 prolog GEMM result
constexpr size_t GIWS_OFF = 28351488;  // [2048][192][24] bf16 gi (n innermost)
constexpr size_t H0WS_OFF = 47225856;  // [2048][24][64] bf16 h0
constexpr size_t WS_NEED  = 53517312;

// t_l: [2048 c][4 octet][8 mm] ushort (128 KB); c = b*256 + o (o<192: hh, o>=192: fc)
#define TOCT(c,q) ((((q) ^ ((c)&3) ^ (((c)>>2)&3) ^ (((c)>>8)&3) ^ (((c)>>10)&3)) & 3))
#define TIDX(c,q,mm) (((c)<<5) + (TOCT(c,q)<<3) + (mm))
// h_l (ushort index): [n][b][i], b in [0,8), i XOR-swizzled by b and n (R2-verified)
#define HL(n,b,i) ((((n)*8+(b))<<6) + ((i) ^ (((b)&7)<<3) ^ ((((n)>>2)&3)<<4)))

__device__ __forceinline__ float bf2f(ushort u){
  union { uint32_t i; float f; } v; v.i = ((uint32_t)u) << 16; return v.f;
}
__device__ __forceinline__ ushort f2bf(float f){
  union { float f; uint32_t i; } v; v.f = f;
  return (ushort)((v.i + 0x7fffu + ((v.i >> 16) & 1u)) >> 16);
}
__device__ __forceinline__ f32x4 mfma16(bf16x8 a, bf16x8 b, f32x4 c){
  return __builtin_amdgcn_mfma_f32_16x16x32_bf16(a, b, c, 0, 0, 0);
}
__device__ __forceinline__ float sigmoidf_(float x){
  float e = __expf(-x); return __builtin_amdgcn_rcpf(1.f + e);
}
__device__ __forceinline__ float tanhf_(float x){
  float e = __expf(-2.f*fabsf(x));
  float r = (1.f - e)*__builtin_amdgcn_rcpf(1.f + e);
  return copysignf(r, x);
}

// ---------------- G row-normalize ----------------
__global__ void k_gnorm(const float* g0, const float* g1, const float* g2, const float* g3, float* gn){
  int t = threadIdx.x;
  if (t >= 96) return;
  int mat = t / 24, row = t % 24;
  const float* G = (mat==0)? g0 : (mat==1)? g1 : (mat==2)? g2 : g3;
  float s = 0.f;
  for (int m=0;m<24;m++) s += fabsf(G[row*24+m]);
  float inv = 1.f/s;
  for (int m=0;m<24;m++) gn[mat*576 + row*24 + m] = G[row*24+m]*inv;
}

// ---------------- weight transpose/cast + bias prep ----------------
__global__ void k_prep(const float* Wih, const float* Winit, const float* Whh, const float* Wfc,
                       const float* bih, const float* bhh, const float* bfc,
                       ushort* wtp, ushort* wthh, ushort* wtfc, float* bgi,
                       float* bhn2, float* bfc2){
  int stride = gridDim.x*blockDim.x;
  int t0 = blockIdx.x*blockDim.x + threadIdx.x;
  for (int f = t0; f < 884736; f += stride){
    int m = f/36864, rr = f - m*36864, o = rr/192, i = rr - o*192;
    wtp[((size_t)m*256 + o)*192 + i] = f2bf(Wih[(size_t)m*36864 + i*192 + o]);
  }
  for (int f = t0; f < 294912; f += stride){
    int m = f/12288, rr = f - m*12288, o = rr/192, i = rr - o*192;
    wtp[((size_t)m*256 + 192 + o)*192 + i] = f2bf(Winit[(size_t)m*12288 + i*64 + o]);
  }
  for (int f = t0; f < 294912; f += stride){
    int m = f/12288, rr = f - m*12288, o = rr/64, i = rr - o*64;
    wthh[((size_t)m*192 + o)*64 + i] = f2bf(Whh[(size_t)m*12288 + i*192 + o]);
  }
  for (int f = t0; f < 98304; f += stride){
    int m = f/4096, rr = f - m*4096, o = rr/64, i = rr - o*64;
    wtfc[((size_t)m*64 + o)*64 + i] = f2bf(Wfc[(size_t)m*4096 + i*64 + o]);
  }
  for (int f = t0; f < 4608; f += stride){
    int o = f % 192;
    bgi[f] = bih[f] + ((o<128) ? bhh[f] : 0.f);
  }
  for (int f = t0; f < 1536; f += stride){
    int o = f/24, n = f - o*24;
    bhn2[f] = bhh[n*192 + 128 + o];
    bfc2[f] = bfc[n*64 + o];
  }
}

// ---------------- prolog per-node GEMM: rec(64b x 192) @ W^T -> t_ws ----------------
__global__ __launch_bounds__(256) void k_p1(const float* x, const float* h, const ushort* wtp,
                                            ushort* t_ws, int tsel, int o_base, int ntt){
  __shared__ ushort A_lds[64*192];
  int tid = threadIdx.x, w = tid>>6, l = tid&63;
  int m = blockIdx.x, b0 = blockIdx.y*64;
  for (int f = tid; f < 64*192; f += 256){
    int b = f/192, i = f - b*192;
    float v = (i < 64) ? x[((size_t)(b0+b)*3 + tsel)*1536 + m*64 + i]
                       : h[((size_t)(b0+b)*24 + m)*128 + (i-64)];
    A_lds[b*192 + (i ^ ((b&7)<<3))] = f2bf(v);
  }
  __syncthreads();
  for (int mt=0; mt<4; mt++){
    for (int nt = w; nt < ntt; nt += 4){
      f32x4 acc = {0.f,0.f,0.f,0.f};
      int rowb = mt*16 + (l&15);
      int og = o_base + nt*16 + (l&15);
      #pragma unroll
      for (int kc=0;kc<6;kc++){
        int i0 = kc*32 + ((l>>4)<<3);
        bf16x8 av = __builtin_bit_cast(bf16x8, *(const uint4*)(A_lds + rowb*192 + (i0 ^ ((rowb&7)<<3))));
        bf16x8 bv = __builtin_bit_cast(bf16x8, *(const uint4*)(wtp + ((size_t)m*256 + og)*192 + i0));
        acc = mfma16(av, bv, acc);
      }
      #pragma unroll
      for (int r=0;r<4;r++){
        int bp = mt*16 + ((l>>4)<<2) + r;
        t_ws[((size_t)(b0+bp)*24 + m)*256 + og] = f2bf(acc[r]);
      }
    }
  }
}

// ---------------- prolog mix: gi = Gn_ih @ t + bias ; h0 = Gn_init @ t + b_init ----------------
__global__ __launch_bounds__(256) void k_p2(const ushort* t_ws, const float* gn, const float* bgi,
                                            const float* binit, ushort* gi_ws, ushort* h0_ws){
  __shared__ ushort t_l[24*256];
  int tid = threadIdx.x; size_t b = blockIdx.x;
  const uint4* src = (const uint4*)(t_ws + b*6144);
  uint4* dst = (uint4*)t_l;
  for (int f = tid; f < 768; f += 256) dst[f] = src[f];
  __syncthreads();
  int o = tid;
  float acc[24];
  if (o < 192){
    const float* gih = gn + 576;
    #pragma unroll
    for (int n=0;n<24;n++) acc[n] = bgi[n*192+o];
    for (int m=0;m<24;m++){
      float tv = bf2f(t_l[m*256+o]);
      #pragma unroll
      for (int n=0;n<24;n++) acc[n] = fmaf(gih[n*24+m], tv, acc[n]);
    }
    uint ov[12];
    #pragma unroll
    for (int q=0;q<12;q++) ov[q] = (uint)f2bf(acc[2*q]) | ((uint)f2bf(acc[2*q+1])<<16);
    uint4* gdst = (uint4*)(gi_ws + (b*192 + o)*24);
    gdst[0] = make_uint4(ov[0],ov[1],ov[2],ov[3]);
    gdst[1] = make_uint4(ov[4],ov[5],ov[6],ov[7]);
    gdst[2] = make_uint4(ov[8],ov[9],ov[10],ov[11]);
  } else {
    int o2 = o - 192;
    const float* gin = gn;
    #pragma unroll
    for (int n=0;n<24;n++) acc[n] = binit[n*64+o2];
    for (int m=0;m<24;m++){
      float tv = bf2f(t_l[m*256 + 192 + o2]);
      #pragma unroll
      for (int n=0;n<24;n++) acc[n] = fmaf(gin[n*24+m], tv, acc[n]);
    }
    #pragma unroll
    for (int n=0;n<24;n++) h0_ws[(b*24+n)*64 + o2] = f2bf(acc[n]);
  }
}

// ---------------- x_t passthrough (NT stores) ----------------
__global__ void k_copy(const f32x4* x, f32x4* out2){
  int i = blockIdx.x*blockDim.x + threadIdx.x;
  for (; i < 2048*384; i += gridDim.x*blockDim.x){
    int b = i/384; int r = i - b*384;
    f32x4 v = x[(size_t)b*1152 + 768 + r];
    __builtin_nontemporal_store(v, &out2[i]);
  }
}

// ---------------- main GRU loop: 256 blocks x 8-batch tile, 16 waves, 2 barriers/step ----------------
// Phase A: fc-GEMM(s-1) + hh-GEMM(s)   (both read h_l = h after step s-1)
// Phase B: fc-mix(s-1)+NT-store + hh-mix(s) (gi re-loaded inline from L2; no hoisted arrays)
__global__ __launch_bounds__(1024,1) void k_main(const ushort* giws, const ushort* h0ws,
    const ushort* wthh, const ushort* wtfc, const float* gn,
    const float* bhn2, const float* bfc2, float* out){
  __shared__ ushort h_l[12288];    // 24n x 8b x 64i, swizzled (24.6 KB)
  __shared__ ushort t_l[65536];    // 2048c x 64B, TOCT layout (128 KB)
  const int tid = threadIdx.x, w = tid>>6, l = tid&63;
  const int lr = l&15, lq = l>>4;
  const int b0 = blockIdx.x*8;

  // zero the q=3 pad octets once
  for (int f = tid; f < 16384; f += 1024){
    int c = f>>3, mm = f&7;
    t_l[TIDX(c,3,mm)] = 0;
  }
  // stage h0 -> h_l (swizzled)
  for (int f = tid; f < 3072; f += 1024){
    int idx = f<<2; int b = idx/1536; int r2 = idx - b*1536; int n = r2>>6; int i = r2&63;
    ushort4 v = *(const ushort4*)(h0ws + (size_t)(b0+b)*1536 + r2);
    *(ushort4*)(h_l + HL(n,b,i)) = v;
  }
  // constant Gn A-fragments (rows n, k=m, zero-padded)
  bf16x8 gnhh[2], gnfc[2];
  #pragma unroll
  for (int nt2=0; nt2<2; nt2++){
    union { ushort s[8]; bf16x8 v; } uh, uf;
    int row = nt2*16 + lr;
    #pragma unroll
    for (int jj=0;jj<8;jj++){
      int m = lq*8 + jj;
      bool ok = (row<24) && (m<24);
      uh.s[jj] = ok ? f2bf(gn[2*576 + row*24 + m]) : (ushort)0;
      uf.s[jj] = ok ? f2bf(gn[3*576 + row*24 + m]) : (ushort)0;
    }
    gnhh[nt2] = uh.v; gnfc[nt2] = uf.v;
  }
  __syncthreads();

  #pragma unroll 1
  for (int s=0; s<=16; s++){
    __syncthreads();
    // ======== Phase A: GEMMs (read h_l, write t_l) ========
    if (s > 0){
      // fc-GEMM(s-1): 6 tasks/wave -> t_l cols 192-255
      #pragma unroll 3
      for (int k=0;k<6;k++){
        int tId = w + k*16, m = tId>>2, nt = tId&3;
        int o = nt*16 + lr;
        const ushort* wb = wtfc + ((((size_t)m<<6) + o)<<6);
        bf16x8 av0 = __builtin_bit_cast(bf16x8, *(const uint4*)(h_l + HL(m, lr&7, lq*8)));
        f32x4 acc = mfma16(av0, __builtin_bit_cast(bf16x8, *(const uint4*)(wb + lq*8)), (f32x4){0.f,0.f,0.f,0.f});
        bf16x8 av1 = __builtin_bit_cast(bf16x8, *(const uint4*)(h_l + HL(m, lr&7, 32 + lq*8)));
        acc = mfma16(av1, __builtin_bit_cast(bf16x8, *(const uint4*)(wb + 32 + lq*8)), acc);
        if (l < 32){
          #pragma unroll
          for (int r=0;r<4;r++){
            int c = (lq*4 + r)*256 + 192 + o;
            t_l[TIDX(c, m>>3, m&7)] = f2bf(acc[r]);
          }
        }
      }
    }
    if (s < 16){
      // hh-GEMM(s): 18 tasks/wave over all 192 W_hh cols -> t_l cols 0-191
      #pragma unroll 3
      for (int k=0;k<18;k++){
        int tId = w + k*16;
        int m = tId/12, col = tId - m*12;
        int o = col*16 + lr;
        const ushort* wb = wthh + (((size_t)m*192 + o)<<6);
        bf16x8 av0 = __builtin_bit_cast(bf16x8, *(const uint4*)(h_l + HL(m, lr&7, lq*8)));
        f32x4 acc = mfma16(av0, __builtin_bit_cast(bf16x8, *(const uint4*)(wb + lq*8)), (f32x4){0.f,0.f,0.f,0.f});
        bf16x8 av1 = __builtin_bit_cast(bf16x8, *(const uint4*)(h_l + HL(m, lr&7, 32 + lq*8)));
        acc = mfma16(av1, __builtin_bit_cast(bf16x8, *(const uint4*)(wb + 32 + lq*8)), acc);
        if (l < 32){
          #pragma unroll
          for (int r=0;r<4;r++){
            int c = (lq*4 + r)*256 + o;
            t_l[TIDX(c, m>>3, m&7)] = f2bf(acc[r]);
          }
        }
      }
    }
    __syncthreads();
    // ======== Phase B: mixes (coords recomputed; gi/bias loads inline from L2) ========
    if (s > 0){
      // fc-mix(s-1): tanh + NT store
      #pragma unroll 2
      for (int k=0;k<4;k++){
        int t = w + k*16;
        int b = t>>3, ot = (t>>1)&3, nt2 = t&1;
        int co = ot*16 + lr, n0 = nt2*16 + lq*4;
        int c = b*256 + 192 + co;
        f32x4 cin = *(const f32x4*)(bfc2 + co*24 + n0);
        bf16x8 bv = __builtin_bit_cast(bf16x8, *(const uint4*)(t_l + (c<<5) + (TOCT(c,lq)<<3)));
        f32x4 fa = mfma16(gnfc[nt2], bv, cin);
        #pragma unroll
        for (int r=0;r<4;r++){
          int n = n0 + r;
          if (n < 24){
            float y = tanhf_(fa[r]);
            __builtin_nontemporal_store(y,
              &out[((size_t)(b0+b)*16 + (s-1))*1536 + (n<<6) + co]);
          }
        }
      }
    }
    if (s < 16){
      // hh-mix(s): fused r/u/n mix + gate math + h_l update (gi from L2)
      #pragma unroll 2
      for (int k=0;k<4;k++){
        int t = w + k*16;
        int b = t>>3, ot = (t>>1)&3, nt2 = t&1;
        int co = ot*16 + lr, n0 = nt2*16 + lq*4;
        size_t gbase = ((size_t)(b0+b)*192 + co)*24 + n0;
        ushort4 gr  = *(const ushort4*)(giws + gbase);
        ushort4 gu  = *(const ushort4*)(giws + gbase + 64*24);
        ushort4 gnn = *(const ushort4*)(giws + gbase + 128*24);
        int cr = b*256 + co;
        bf16x8 bvr = __builtin_bit_cast(bf16x8, *(const uint4*)(t_l + (cr<<5) + (TOCT(cr,lq)<<3)));
        int cu = cr + 64;
        bf16x8 bvu = __builtin_bit_cast(bf16x8, *(const uint4*)(t_l + (cu<<5) + (TOCT(cu,lq)<<3)));
        int cn = cr + 128;
        bf16x8 bvn = __builtin_bit_cast(bf16x8, *(const uint4*)(t_l + (cn<<5) + (TOCT(cn,lq)<<3)));
        f32x4 cin_r = { bf2f(gr.x), bf2f(gr.y), bf2f(gr.z), bf2f(gr.w) };
        f32x4 cin_u = { bf2f(gu.x), bf2f(gu.y), bf2f(gu.z), bf2f(gu.w) };
        f32x4 cin_n = *(const f32x4*)(bhn2 + co*24 + n0);
        f32x4 fr = mfma16(gnhh[nt2], bvr, cin_r);
        f32x4 fu = mfma16(gnhh[nt2], bvu, cin_u);
        f32x4 fn = mfma16(gnhh[nt2], bvn, cin_n);
        float gin[4] = { bf2f(gnn.x), bf2f(gnn.y), bf2f(gnn.z), bf2f(gnn.w) };
        #pragma unroll
        for (int r=0;r<4;r++){
          int n = n0 + r;
          if (n < 24){
            float rg = sigmoidf_(fr[r]);
            float ug = sigmoidf_(fu[r]);
            float nn = tanhf_(gin[r] + rg*fn[r]);
            float hp = bf2f(h_l[HL(n, b, co)]);
            float hv = (1.f-ug)*nn + ug*hp;
            h_l[HL(n, b, co)] = f2bf(hv);
          }
        }
      }
    }
  }
}

extern "C" void kernel_launch(void* const* d_in, const int* in_sizes, int n_in,
                              void* d_out, int out_size, void* d_ws, size_t ws_size,
                              hipStream_t stream){
  if (ws_size < WS_NEED) return;
  const float* x     = (const float*)d_in[0];
  const float* h     = (const float*)d_in[1];
  const float* Winit = (const float*)d_in[4];
  const float* binit = (const float*)d_in[5];
  const float* Ginit = (const float*)d_in[6];
  const float* Wih   = (const float*)d_in[7];
  const float* bih   = (const float*)d_in[8];
  const float* Gih   = (const float*)d_in[9];
  const float* Whh   = (const float*)d_in[10];
  const float* bhh   = (const float*)d_in[11];
  const float* Ghh   = (const float*)d_in[12];
  const float* Wfc   = (const float*)d_in[13];
  const float* bfc   = (const float*)d_in[14];
  const float* Gfc   = (const float*)d_in[15];
  char* ws = (char*)d_ws;
  ushort* wtp  = (ushort*)(ws + WTP_OFF);
  ushort* wthh = (ushort*)(ws + WTHH_OFF);
  ushort* wtfc = (ushort*)(ws + WTFC_OFF);
  float*  gn   = (float*)(ws + GN_OFF);
  float*  bgi  = (float*)(ws + BGI_OFF);
  float*  bhn2 = (float*)(ws + BHN2_OFF);
  float*  bfc2 = (float*)(ws + BFC2_OFF);
  ushort* tws  = (ushort*)(ws + TWS_OFF);
  ushort* giws = (ushort*)(ws + GIWS_OFF);
  ushort* h0ws = (ushort*)(ws + H0WS_OFF);
  float* out  = (float*)d_out;
  float* out2 = out + (size_t)2048*16*1536;

  k_gnorm<<<1, 128, 0, stream>>>(Ginit, Gih, Ghh, Gfc, gn);
  k_prep<<<512, 256, 0, stream>>>(Wih, Winit, Whh, Wfc, bih, bhh, bfc, wtp, wthh, wtfc, bgi, bhn2, bfc2);
  k_p1<<<dim3(24,32), 256, 0, stream>>>(x, h, wtp, tws, 2, 0, 12);
  k_p1<<<dim3(24,32), 256, 0, stream>>>(x, h, wtp, tws, 1, 192, 4);
  k_p2<<<2048, 256, 0, stream>>>(tws, gn, bgi, binit, giws, h0ws);
  k_copy<<<2048, 256, 0, stream>>>((const f32x4*)x, (f32x4*)out2);
  k_main<<<256, 1024, 0, stream>>>(giws, h0ws, wthh, wtfc, gn, bhn2, bfc2, out);
}

// Round 16
// 576.492 us; speedup vs baseline: 1.4838x; 1.0171x over previous
//
#include <hip/hip_runtime.h>
#include <hip/hip_bf16.h>
#include <cstdint>

typedef __bf16 bf16x8 __attribute__((ext_vector_type(8)));
typedef float  f32x4  __attribute__((ext_vector_type(4)));

// ---------------- workspace layout (bytes) ----------------
constexpr size_t WTP_OFF  = 0;         // [24][256][192] bf16 prolog W^T
constexpr size_t WTHH_OFF = 2359296;   // [24][192][64]  bf16 W_hh^T per node
constexpr size_t WTFC_OFF = 2949120;   // [24][64][64]   bf16 W_fc^T per node
constexpr size_t GN_OFF   = 3145728;   // [4][24][24] f32 row-L1-normalized
constexpr size_t BGI_OFF  = 3154944;   // [24][192] f32 folded gi bias
constexpr size_t BHN2_OFF = 3173376;   // [64 j][24 n] f32 b_hh n-slice, n-contig
constexpr size_t BFC2_OFF = 3179520;   // [64 o][24 n] f32 b_fc, n-contig
constexpr size_t TWS_OFF  = 3185664;   // [2048][24][256] bf16 prolog GEMM result
constexpr size_t GIWS_OFF = 28351488;  // [2048][192][24] bf16 gi (n innermost)
constexpr size_t H0WS_OFF = 47225856;  // [2048][24][64] bf16 h0
constexpr size_t WS_NEED  = 53517312;

// t_l: [2048 c][4 octet][8 mm] ushort (128 KB); c = b*256 + o (o<192: hh, o>=192: fc)
#define TOCT(c,q) ((((q) ^ ((c)&3) ^ (((c)>>2)&3) ^ (((c)>>8)&3) ^ (((c)>>10)&3)) & 3))
#define TIDX(c,q,mm) (((c)<<5) + (TOCT(c,q)<<3) + (mm))
// h_l (ushort index): [n][b][i], b in [0,8), i XOR-swizzled by b and n (R2-verified)
#define HL(n,b,i) ((((n)*8+(b))<<6) + ((i) ^ (((b)&7)<<3) ^ ((((n)>>2)&3)<<4)))

__device__ __forceinline__ float bf2f(ushort u){
  union { uint32_t i; float f; } v; v.i = ((uint32_t)u) << 16; return v.f;
}
__device__ __forceinline__ ushort f2bf(float f){
  union { float f; uint32_t i; } v; v.f = f;
  return (ushort)((v.i + 0x7fffu + ((v.i >> 16) & 1u)) >> 16);
}
// RNE pack of two f32 -> one uint (lo in low 16). Composition of the proven f2bf.
__device__ __forceinline__ uint pk2(float lo, float hi){
  return (uint)f2bf(lo) | ((uint)f2bf(hi) << 16);
}
__device__ __forceinline__ f32x4 mfma16(bf16x8 a, bf16x8 b, f32x4 c){
  return __builtin_amdgcn_mfma_f32_16x16x32_bf16(a, b, c, 0, 0, 0);
}
__device__ __forceinline__ float sigmoidf_(float x){
  float e = __expf(-x); return __builtin_amdgcn_rcpf(1.f + e);
}
__device__ __forceinline__ float tanhf_(float x){
  float e = __expf(-2.f*fabsf(x));
  float r = (1.f - e)*__builtin_amdgcn_rcpf(1.f + e);
  return copysignf(r, x);
}

// ---------------- weight transpose/cast + bias prep + G row-normalize ----------------
__global__ void k_prep(const float* Wih, const float* Winit, const float* Whh, const float* Wfc,
                       const float* bih, const float* bhh, const float* bfc,
                       const float* g0, const float* g1, const float* g2, const float* g3,
                       ushort* wtp, ushort* wthh, ushort* wtfc, float* bgi,
                       float* bhn2, float* bfc2, float* gn){
  int stride = gridDim.x*blockDim.x;
  int t0 = blockIdx.x*blockDim.x + threadIdx.x;
  if (blockIdx.x == 0 && threadIdx.x < 96){
    int t = threadIdx.x;
    int mat = t / 24, row = t % 24;
    const float* G = (mat==0)? g0 : (mat==1)? g1 : (mat==2)? g2 : g3;
    float s = 0.f;
    for (int m=0;m<24;m++) s += fabsf(G[row*24+m]);
    float inv = 1.f/s;
    for (int m=0;m<24;m++) gn[mat*576 + row*24 + m] = G[row*24+m]*inv;
  }
  for (int f = t0; f < 884736; f += stride){
    int m = f/36864, rr = f - m*36864, o = rr/192, i = rr - o*192;
    wtp[((size_t)m*256 + o)*192 + i] = f2bf(Wih[(size_t)m*36864 + i*192 + o]);
  }
  for (int f = t0; f < 294912; f += stride){
    int m = f/12288, rr = f - m*12288, o = rr/192, i = rr - o*192;
    wtp[((size_t)m*256 + 192 + o)*192 + i] = f2bf(Winit[(size_t)m*12288 + i*64 + o]);
  }
  for (int f = t0; f < 294912; f += stride){
    int m = f/12288, rr = f - m*12288, o = rr/64, i = rr - o*64;
    wthh[((size_t)m*192 + o)*64 + i] = f2bf(Whh[(size_t)m*12288 + i*192 + o]);
  }
  for (int f = t0; f < 98304; f += stride){
    int m = f/4096, rr = f - m*4096, o = rr/64, i = rr - o*64;
    wtfc[((size_t)m*64 + o)*64 + i] = f2bf(Wfc[(size_t)m*4096 + i*64 + o]);
  }
  for (int f = t0; f < 4608; f += stride){
    int o = f % 192;
    bgi[f] = bih[f] + ((o<128) ? bhh[f] : 0.f);
  }
  for (int f = t0; f < 1536; f += stride){
    int o = f/24, n = f - o*24;
    bhn2[f] = bhh[n*192 + 128 + o];
    bfc2[f] = bfc[n*64 + o];
  }
}

// ---------------- prolog per-node GEMM: rec(64b x 192) @ W^T -> t_ws ----------------
// blockIdx.z: 0 -> gi pre-mix (x_t, cols 0-191), 1 -> h0 pre-mix (x_{t-1}, cols 192-255)
__global__ __launch_bounds__(256) void k_p1(const float* x, const float* h, const ushort* wtp,
                                            ushort* t_ws){
  __shared__ ushort A_lds[64*192];
  int tid = threadIdx.x, w = tid>>6, l = tid&63;
  int m = blockIdx.x, b0 = blockIdx.y*64;
  const int z = blockIdx.z;
  const int tsel = z ? 1 : 2, o_base = z ? 192 : 0, ntt = z ? 4 : 12;
  // vectorized staging: 3072 float4 (64 rows x 48 f4)
  for (int f = tid; f < 3072; f += 256){
    int b = f/48, r4 = f - b*48;
    f32x4 v;
    if (r4 < 16) v = *((const f32x4*)(x + ((size_t)(b0+b)*3 + tsel)*1536 + m*64) + r4);
    else         v = *((const f32x4*)(h + ((size_t)(b0+b)*24 + m)*128) + (r4-16));
    int i = r4*4;
    uint pa = pk2(v[0], v[1]), pb = pk2(v[2], v[3]);
    *(uint2*)(A_lds + b*192 + (i ^ ((b&7)<<3))) = make_uint2(pa, pb);
  }
  __syncthreads();
  for (int mt=0; mt<4; mt++){
    for (int nt = w; nt < ntt; nt += 4){
      f32x4 acc = {0.f,0.f,0.f,0.f};
      int rowb = mt*16 + (l&15);
      int og = o_base + nt*16 + (l&15);
      #pragma unroll
      for (int kc=0;kc<6;kc++){
        int i0 = kc*32 + ((l>>4)<<3);
        bf16x8 av = __builtin_bit_cast(bf16x8, *(const uint4*)(A_lds + rowb*192 + (i0 ^ ((rowb&7)<<3))));
        bf16x8 bv = __builtin_bit_cast(bf16x8, *(const uint4*)(wtp + ((size_t)m*256 + og)*192 + i0));
        acc = mfma16(av, bv, acc);
      }
      uint p01 = pk2(acc[0], acc[1]), p23 = pk2(acc[2], acc[3]);
      int bp = mt*16 + ((l>>4)<<2);
      t_ws[((size_t)(b0+bp  )*24 + m)*256 + og] = (ushort)p01;
      t_ws[((size_t)(b0+bp+1)*24 + m)*256 + og] = (ushort)(p01>>16);
      t_ws[((size_t)(b0+bp+2)*24 + m)*256 + og] = (ushort)p23;
      t_ws[((size_t)(b0+bp+3)*24 + m)*256 + og] = (ushort)(p23>>16);
    }
  }
}

// ---------------- prolog mix + x_t passthrough ----------------
__global__ __launch_bounds__(256) void k_p2(const ushort* t_ws, const float* gn, const float* bgi,
                                            const float* binit, ushort* gi_ws, ushort* h0_ws,
                                            const float* x, f32x4* out2){
  __shared__ ushort t_l[24*256];
  int tid = threadIdx.x; size_t b = blockIdx.x;
  const uint4* src = (const uint4*)(t_ws + b*6144);
  uint4* dst = (uint4*)t_l;
  for (int f = tid; f < 768; f += 256) dst[f] = src[f];
  // x_t passthrough (independent of barrier)
  {
    const f32x4* xs = (const f32x4*)x + b*1152 + 768;
    f32x4* od = out2 + b*384;
    for (int f = tid; f < 384; f += 256)
      __builtin_nontemporal_store(xs[f], &od[f]);
  }
  __syncthreads();
  int o = tid;
  float acc[24];
  if (o < 192){
    const float* gih = gn + 576;
    #pragma unroll
    for (int n=0;n<24;n++) acc[n] = bgi[n*192+o];
    for (int m=0;m<24;m++){
      float tv = bf2f(t_l[m*256+o]);
      #pragma unroll
      for (int n=0;n<24;n++) acc[n] = fmaf(gih[n*24+m], tv, acc[n]);
    }
    uint ov[12];
    #pragma unroll
    for (int q=0;q<12;q++) ov[q] = pk2(acc[2*q], acc[2*q+1]);
    uint4* gdst = (uint4*)(gi_ws + (b*192 + o)*24);
    gdst[0] = make_uint4(ov[0],ov[1],ov[2],ov[3]);
    gdst[1] = make_uint4(ov[4],ov[5],ov[6],ov[7]);
    gdst[2] = make_uint4(ov[8],ov[9],ov[10],ov[11]);
  } else {
    int o2 = o - 192;
    const float* gin = gn;
    #pragma unroll
    for (int n=0;n<24;n++) acc[n] = binit[n*64+o2];
    for (int m=0;m<24;m++){
      float tv = bf2f(t_l[m*256 + 192 + o2]);
      #pragma unroll
      for (int n=0;n<24;n++) acc[n] = fmaf(gin[n*24+m], tv, acc[n]);
    }
    #pragma unroll
    for (int n=0;n<24;n++) h0_ws[(b*24+n)*64 + o2] = f2bf(acc[n]);
  }
}

// ---------------- main GRU loop: 256 blocks x 8-batch tile, 16 waves, 2 barriers/step ----------------
__global__ __launch_bounds__(1024,1) void k_main(const ushort* giws, const ushort* h0ws,
    const ushort* wthh, const ushort* wtfc, const float* gn,
    const float* bhn2, const float* bfc2, float* out){
  __shared__ ushort h_l[12288];    // 24n x 8b x 64i, swizzled (24.6 KB)
  __shared__ ushort t_l[65536];    // 2048c x 64B, TOCT layout (128 KB)
  const int tid = threadIdx.x, w = tid>>6, l = tid&63;
  const int lr = l&15, lq = l>>4;
  const int b0 = blockIdx.x*8;

  // zero the q=3 pad octets once
  for (int f = tid; f < 16384; f += 1024){
    int c = f>>3, mm = f&7;
    t_l[TIDX(c,3,mm)] = 0;
  }
  // stage h0 -> h_l (swizzled)
  for (int f = tid; f < 3072; f += 1024){
    int idx = f<<2; int b = idx/1536; int r2 = idx - b*1536; int n = r2>>6; int i = r2&63;
    ushort4 v = *(const ushort4*)(h0ws + (size_t)(b0+b)*1536 + r2);
    *(ushort4*)(h_l + HL(n,b,i)) = v;
  }
  // constant Gn A-fragments (rows n, k=m, zero-padded)
  bf16x8 gnhh[2], gnfc[2];
  #pragma unroll
  for (int nt2=0; nt2<2; nt2++){
    union { ushort s[8]; bf16x8 v; } uh, uf;
    int row = nt2*16 + lr;
    #pragma unroll
    for (int jj=0;jj<8;jj++){
      int m = lq*8 + jj;
      bool ok = (row<24) && (m<24);
      uh.s[jj] = ok ? f2bf(gn[2*576 + row*24 + m]) : (ushort)0;
      uf.s[jj] = ok ? f2bf(gn[3*576 + row*24 + m]) : (ushort)0;
    }
    gnhh[nt2] = uh.v; gnfc[nt2] = uf.v;
  }
  __syncthreads();

  #pragma unroll 1
  for (int s=0; s<=16; s++){
    __syncthreads();
    // ======== Phase A: GEMMs (read h_l, write t_l) ========
    if (s > 0){
      // fc-GEMM(s-1): 6 tasks/wave -> t_l cols 192-255
      #pragma unroll 3
      for (int k=0;k<6;k++){
        int tId = w + k*16, m = tId>>2, nt = tId&3;
        int o = nt*16 + lr;
        const ushort* wb = wtfc + ((((size_t)m<<6) + o)<<6);
        bf16x8 av0 = __builtin_bit_cast(bf16x8, *(const uint4*)(h_l + HL(m, lr&7, lq*8)));
        f32x4 acc = mfma16(av0, __builtin_bit_cast(bf16x8, *(const uint4*)(wb + lq*8)), (f32x4){0.f,0.f,0.f,0.f});
        bf16x8 av1 = __builtin_bit_cast(bf16x8, *(const uint4*)(h_l + HL(m, lr&7, 32 + lq*8)));
        acc = mfma16(av1, __builtin_bit_cast(bf16x8, *(const uint4*)(wb + 32 + lq*8)), acc);
        if (l < 32){
          uint p01 = pk2(acc[0], acc[1]), p23 = pk2(acc[2], acc[3]);
          int cb = (lq*4)*256 + 192 + o;
          t_l[TIDX(cb      , m>>3, m&7)] = (ushort)p01;
          t_l[TIDX(cb + 256, m>>3, m&7)] = (ushort)(p01>>16);
          t_l[TIDX(cb + 512, m>>3, m&7)] = (ushort)p23;
          t_l[TIDX(cb + 768, m>>3, m&7)] = (ushort)(p23>>16);
        }
      }
    }
    if (s < 16){
      // hh-GEMM(s): 18 tasks/wave over all 192 W_hh cols -> t_l cols 0-191
      #pragma unroll 3
      for (int k=0;k<18;k++){
        int tId = w + k*16;
        int m = tId/12, col = tId - m*12;
        int o = col*16 + lr;
        const ushort* wb = wthh + (((size_t)m*192 + o)<<6);
        bf16x8 av0 = __builtin_bit_cast(bf16x8, *(const uint4*)(h_l + HL(m, lr&7, lq*8)));
        f32x4 acc = mfma16(av0, __builtin_bit_cast(bf16x8, *(const uint4*)(wb + lq*8)), (f32x4){0.f,0.f,0.f,0.f});
        bf16x8 av1 = __builtin_bit_cast(bf16x8, *(const uint4*)(h_l + HL(m, lr&7, 32 + lq*8)));
        acc = mfma16(av1, __builtin_bit_cast(bf16x8, *(const uint4*)(wb + 32 + lq*8)), acc);
        if (l < 32){
          uint p01 = pk2(acc[0], acc[1]), p23 = pk2(acc[2], acc[3]);
          int cb = (lq*4)*256 + o;
          t_l[TIDX(cb      , m>>3, m&7)] = (ushort)p01;
          t_l[TIDX(cb + 256, m>>3, m&7)] = (ushort)(p01>>16);
          t_l[TIDX(cb + 512, m>>3, m&7)] = (ushort)p23;
          t_l[TIDX(cb + 768, m>>3, m&7)] = (ushort)(p23>>16);
        }
      }
    }
    __syncthreads();
    // ======== Phase B: mixes (coords recomputed; gi/bias loads inline from L2) ========
    if (s > 0){
      // fc-mix(s-1): tanh + NT store
      #pragma unroll 2
      for (int k=0;k<4;k++){
        int t = w + k*16;
        int b = t>>3, ot = (t>>1)&3, nt2 = t&1;
        int co = ot*16 + lr, n0 = nt2*16 + lq*4;
        int c = b*256 + 192 + co;
        f32x4 cin = *(const f32x4*)(bfc2 + co*24 + ((n0<24)?n0:0));
        bf16x8 bv = __builtin_bit_cast(bf16x8, *(const uint4*)(t_l + (c<<5) + (TOCT(c,lq)<<3)));
        f32x4 fa = mfma16(gnfc[nt2], bv, cin);
        #pragma unroll
        for (int r=0;r<4;r++){
          int n = n0 + r;
          if (n < 24){
            float y = tanhf_(fa[r]);
            __builtin_nontemporal_store(y,
              &out[((size_t)(b0+b)*16 + (s-1))*1536 + (n<<6) + co]);
          }
        }
      }
    }
    if (s < 16){
      // hh-mix(s): fused r/u/n mix + gate math + h_l update (gi from L2)
      #pragma unroll 2
      for (int k=0;k<4;k++){
        int t = w + k*16;
        int b = t>>3, ot = (t>>1)&3, nt2 = t&1;
        int co = ot*16 + lr, n0 = nt2*16 + lq*4;
        int nc = (n0 < 24) ? n0 : 0;    // clamped for loads; writes guarded
        size_t gbase = ((size_t)(b0+b)*192 + co)*24 + nc;
        ushort4 gr  = *(const ushort4*)(giws + gbase);
        ushort4 gu  = *(const ushort4*)(giws + gbase + 64*24);
        ushort4 gnn = *(const ushort4*)(giws + gbase + 128*24);
        int cr = b*256 + co;
        bf16x8 bvr = __builtin_bit_cast(bf16x8, *(const uint4*)(t_l + (cr<<5) + (TOCT(cr,lq)<<3)));
        int cu = cr + 64;
        bf16x8 bvu = __builtin_bit_cast(bf16x8, *(const uint4*)(t_l + (cu<<5) + (TOCT(cu,lq)<<3)));
        int cn = cr + 128;
        bf16x8 bvn = __builtin_bit_cast(bf16x8, *(const uint4*)(t_l + (cn<<5) + (TOCT(cn,lq)<<3)));
        f32x4 cin_r = { bf2f(gr.x), bf2f(gr.y), bf2f(gr.z), bf2f(gr.w) };
        f32x4 cin_u = { bf2f(gu.x), bf2f(gu.y), bf2f(gu.z), bf2f(gu.w) };
        f32x4 cin_n = *(const f32x4*)(bhn2 + co*24 + nc);
        f32x4 fr = mfma16(gnhh[nt2], bvr, cin_r);
        f32x4 fu = mfma16(gnhh[nt2], bvu, cin_u);
        f32x4 fn = mfma16(gnhh[nt2], bvn, cin_n);
        float gin[4] = { bf2f(gnn.x), bf2f(gnn.y), bf2f(gnn.z), bf2f(gnn.w) };
        float hv[4];
        #pragma unroll
        for (int r=0;r<4;r++){
          float rg = sigmoidf_(fr[r]);
          float ug = sigmoidf_(fu[r]);
          float nn = tanhf_(gin[r] + rg*fn[r]);
          float hp = bf2f(h_l[HL(nc + r, b, co)]);
          hv[r] = (1.f-ug)*nn + ug*hp;
        }
        if (n0 < 24){   // n-quads are all-or-nothing valid (n0 in {0,4,...,20} vs {24,28})
          uint p01 = pk2(hv[0], hv[1]), p23 = pk2(hv[2], hv[3]);
          h_l[HL(n0  , b, co)] = (ushort)p01;
          h_l[HL(n0+1, b, co)] = (ushort)(p01>>16);
          h_l[HL(n0+2, b, co)] = (ushort)p23;
          h_l[HL(n0+3, b, co)] = (ushort)(p23>>16);
        }
      }
    }
  }
}

extern "C" void kernel_launch(void* const* d_in, const int* in_sizes, int n_in,
                              void* d_out, int out_size, void* d_ws, size_t ws_size,
                              hipStream_t stream){
  if (ws_size < WS_NEED) return;
  const float* x     = (const float*)d_in[0];
  const float* h     = (const float*)d_in[1];
  const float* Winit = (const float*)d_in[4];
  const float* binit = (const float*)d_in[5];
  const float* Ginit = (const float*)d_in[6];
  const float* Wih   = (const float*)d_in[7];
  const float* bih   = (const float*)d_in[8];
  const float* Gih   = (const float*)d_in[9];
  const float* Whh   = (const float*)d_in[10];
  const float* bhh   = (const float*)d_in[11];
  const float* Ghh   = (const float*)d_in[12];
  const float* Wfc   = (const float*)d_in[13];
  const float* bfc   = (const float*)d_in[14];
  const float* Gfc   = (const float*)d_in[15];
  char* ws = (char*)d_ws;
  ushort* wtp  = (ushort*)(ws + WTP_OFF);
  ushort* wthh = (ushort*)(ws + WTHH_OFF);
  ushort* wtfc = (ushort*)(ws + WTFC_OFF);
  float*  gn   = (float*)(ws + GN_OFF);
  float*  bgi  = (float*)(ws + BGI_OFF);
  float*  bhn2 = (float*)(ws + BHN2_OFF);
  float*  bfc2 = (float*)(ws + BFC2_OFF);
  ushort* tws  = (ushort*)(ws + TWS_OFF);
  ushort* giws = (ushort*)(ws + GIWS_OFF);
  ushort* h0ws = (ushort*)(ws + H0WS_OFF);
  float* out  = (float*)d_out;
  float* out2 = out + (size_t)2048*16*1536;

  k_prep<<<512, 256, 0, stream>>>(Wih, Winit, Whh, Wfc, bih, bhh, bfc,
                                  Ginit, Gih, Ghh, Gfc,
                                  wtp, wthh, wtfc, bgi, bhn2, bfc2, gn);
  k_p1<<<dim3(24,32,2), 256, 0, stream>>>(x, h, wtp, tws);
  k_p2<<<2048, 256, 0, stream>>>(tws, gn, bgi, binit, giws, h0ws, x, (f32x4*)out2);
  k_main<<<256, 1024, 0, stream>>>(giws, h0ws, wthh, wtfc, gn, bhn2, bfc2, out);
}